// Round 2
// baseline (188.572 us; speedup 1.0000x reference)
//
#include <hip/hip_runtime.h>

// EfficientAdditiveAttention  B=8, L=512, D=128
//
// combined(q,k) = sum_d w_all[d]*tanh(Q+K)  -> softmax_k -> @V
// tanh(z) = 1 - 2/(1+e^{2z}); constant terms are softmax-invariant and dropped.
// Q,K pre-scaled by 2*log2(e) so E = exp2(q~+k~) = e^{2z}.
// Per d-quad, the four w_i/(1+E_i) terms are combined over a common
// denominator: 4 exp2 + 1 rcp per 4 elements (trans-pipe is the bottleneck).

#define BB 8
#define LL 512
#define DD 128
#define NROW (BB*LL)            // 4096 rows
#define MATN (NROW*DD)          // 524288 elements per matrix

static constexpr float C1 = 2.8853900817779268f;   // 2*log2(e)
static constexpr float C2 = -2.8853900817779268f;  // -2*log2(e)
static constexpr float INV_SCALE = 0.08838834764831845f; // 1/sqrt(128)

__device__ __forceinline__ float fast_exp2(float x) { return __builtin_amdgcn_exp2f(x); }
__device__ __forceinline__ float fast_rcp(float x)  { return __builtin_amdgcn_rcpf(x); }

// ---------------------------------------------------------------------------
// Projection: out = X @ W.T + b (Q,K scaled by C1). 32-row x 128-col tiles,
// 384 blocks x 256 threads (3 blocks/CU at 42 KB LDS). Thread: 4 rows x 4 cols.
// ---------------------------------------------------------------------------
__global__ __launch_bounds__(256) void proj_kernel(
    const float* __restrict__ query, const float* __restrict__ key,
    const float* __restrict__ value,
    const float* __restrict__ Wq, const float* __restrict__ bq,
    const float* __restrict__ Wk, const float* __restrict__ bk,
    const float* __restrict__ Wv, const float* __restrict__ bv,
    const float* __restrict__ wd, const float* __restrict__ wsg,
    const float* __restrict__ wt, float* __restrict__ ws)
{
    __shared__ __align__(16) float Wl[128 * 66];   // 33792 B
    __shared__ __align__(16) float Xl[32 * 66];    //  8448 B

    const int bx = blockIdx.x;
    const int m  = bx >> 7;              // 0:Q 1:K 2:V  (128 row-tiles each)
    const int r0 = (bx & 127) * 32;
    const float* X    = (m == 0) ? query : (m == 1) ? key : value;
    const float* W    = (m == 0) ? Wq    : (m == 1) ? Wk  : Wv;
    const float* bias = (m == 0) ? bq    : (m == 1) ? bk  : bv;
    float* outp = ws + (size_t)m * MATN;
    const float scale = (m == 2) ? 1.0f : C1;
    const int t = threadIdx.x;

    // w_all (128 f) + w_pair (64 f) -> ws tail, by block 0
    if (bx == 0 && t < 64) {
        float wa0 = INV_SCALE + wd[2*t]   + wsg[2*t]   + wt[2*t];
        float wa1 = INV_SCALE + wd[2*t+1] + wsg[2*t+1] + wt[2*t+1];
        ws[(size_t)3 * MATN + 2*t]     = wa0;
        ws[(size_t)3 * MATN + 2*t + 1] = wa1;
        ws[(size_t)3 * MATN + 128 + t] = wa0 + wa1;
    }

    const int cg = t & 31;   // cols: cg + 32*j
    const int rg = t >> 5;   // rows: rg*4 + i

    float acc[4][4];
    #pragma unroll
    for (int j = 0; j < 4; ++j) {
        float bj = bias[cg + 32 * j];
        #pragma unroll
        for (int i = 0; i < 4; ++i) acc[i][j] = bj;
    }

    const float4* Wsrc = (const float4*)W;
    const float4* Xsrc = (const float4*)X;

    for (int h = 0; h < 2; ++h) {            // K-dim halves (64 each)
        __syncthreads();
        // stage W half: 128 rows x 16 float4
        #pragma unroll
        for (int j = 0; j < 8; ++j) {
            int g = t + j * 256;             // 0..2047
            int c = g >> 4, f4 = g & 15;
            float4 v = Wsrc[c * 32 + h * 16 + f4];
            float* dst = &Wl[c * 66 + f4 * 4];
            *(float2*)dst       = make_float2(v.x, v.y);
            *(float2*)(dst + 2) = make_float2(v.z, v.w);
        }
        // stage X half: 32 rows x 16 float4
        #pragma unroll
        for (int j = 0; j < 2; ++j) {
            int g = t + j * 256;             // 0..511
            int r = g >> 4, f4 = g & 15;
            float4 v = Xsrc[(r0 + r) * 32 + h * 16 + f4];
            float* dst = &Xl[r * 66 + f4 * 4];
            *(float2*)dst       = make_float2(v.x, v.y);
            *(float2*)(dst + 2) = make_float2(v.z, v.w);
        }
        __syncthreads();

        #pragma unroll 4
        for (int dg = 0; dg < 32; ++dg) {
            float2 bf[4];
            #pragma unroll
            for (int j = 0; j < 4; ++j)
                bf[j] = *(const float2*)&Wl[(cg + 32 * j) * 66 + 2 * dg];
            float2 af[4];
            #pragma unroll
            for (int i = 0; i < 4; ++i)
                af[i] = *(const float2*)&Xl[(rg * 4 + i) * 66 + 2 * dg];
            #pragma unroll
            for (int i = 0; i < 4; ++i)
                #pragma unroll
                for (int j = 0; j < 4; ++j)
                    acc[i][j] += af[i].x * bf[j].x + af[i].y * bf[j].y;
        }
    }

    #pragma unroll
    for (int i = 0; i < 4; ++i) {
        int r = r0 + rg * 4 + i;
        #pragma unroll
        for (int j = 0; j < 4; ++j)
            outp[(size_t)r * DD + cg + 32 * j] = acc[i][j] * scale;
    }
}

// ---------------------------------------------------------------------------
// Attention. 512 blocks x 512 threads. Block = 8 q-rows (one per wave).
// Pass A: K tiles in LDS granule layout [d-pair][k] (stride 65 f2) ->
// lane-owns-k reads are contiguous (conflict-free). Quad-rational sigmoid
// combine: 4 exp2 + 1 rcp per 4 elements.
// Pass B: V tile [k][128] unpadded; waves split the tile's k-range 8-ways,
// each accumulates partials for all 8 q; log2 cross-wave reduce via P buffer.
// ---------------------------------------------------------------------------
__global__ __launch_bounds__(512) void attn_kernel(
    const float* __restrict__ ws, float* __restrict__ out)
{
    __shared__ __align__(16) float KV[64 * 65 * 2]; // 33280 B (K granule / V [k][128])
    __shared__ __align__(16) float P[8 * 512];      // 16384 B (p; reused for reduce)
    __shared__ float psumArr[8];

    const float* Qp   = ws;
    const float* Kp   = ws + (size_t)MATN;
    const float* Vp   = ws + (size_t)2 * MATN;
    const float4* W4  = (const float4*)(ws + (size_t)3 * MATN);
    const float2* WP2 = (const float2*)(ws + (size_t)3 * MATN + 128);

    const int bx   = blockIdx.x;
    const int b    = bx >> 6;
    const int q0   = bx * 8;
    const int wave = __builtin_amdgcn_readfirstlane((int)threadIdx.x >> 6);
    const int lane = threadIdx.x & 63;
    const int q    = q0 + wave;

    const float4* __restrict__ Q4 = (const float4*)(Qp + (size_t)q * DD); // uniform
    const float* __restrict__ Kb  = Kp + (size_t)b * (LL * DD);
    const float* __restrict__ Vb  = Vp + (size_t)b * (LL * DD);
    float2* KV2 = (float2*)KV;

    // ---------------- Pass A ----------------
    float psum = 0.f;

    for (int tt = 0; tt < 8; ++tt) {
        __syncthreads();
        {   // stage K tile -> granule layout [g][k], g-stride 65 float2
            const float4* src = (const float4*)(Kb + (size_t)tt * 64 * DD);
            #pragma unroll
            for (int j = 0; j < 4; ++j) {
                int g = threadIdx.x + j * 512;       // 0..2047
                int k = g >> 5, c4 = g & 31;
                float4 v = src[g];
                KV2[(2 * c4) * 65 + k]     = make_float2(v.x, v.y);
                KV2[(2 * c4 + 1) * 65 + k] = make_float2(v.z, v.w);
            }
        }
        __syncthreads();

        float s = 0.f;
        #pragma unroll 8
        for (int i = 0; i < 32; ++i) {               // d-quads
            float4 qv  = Q4[i];                      // wave-uniform (s_load)
            float4 wv  = W4[i];
            float2 wp  = WP2[i];
            float2 k01 = KV2[(2 * i) * 65 + lane];
            float2 k23 = KV2[(2 * i + 1) * 65 + lane];
            float E1 = fast_exp2(qv.x + k01.x);
            float E2 = fast_exp2(qv.y + k01.y);
            float E3 = fast_exp2(qv.z + k23.x);
            float E4 = fast_exp2(qv.w + k23.y);
            float n12 = fmaf(wv.x, E2, fmaf(wv.y, E1, wp.x));
            float n34 = fmaf(wv.z, E4, fmaf(wv.w, E3, wp.y));
            float b12 = fmaf(E1, E2, 1.0f + E1 + E2);   // (1+E1)(1+E2)
            float b34 = fmaf(E3, E4, 1.0f + E3 + E4);
            float num = fmaf(n34, b12, n12 * b34);
            s = fmaf(num, fast_rcp(b12 * b34), s);
        }
        float p = fast_exp2(C2 * s);
        P[wave * 512 + tt * 64 + lane] = p;
        psum += p;
    }

    #pragma unroll
    for (int off = 32; off; off >>= 1) psum += __shfl_xor(psum, off);
    if (lane == 0) psumArr[wave] = psum;

    // ---------------- Pass B: partial PV per wave (k-slice), then reduce ----
    float ax[8], ay[8];
    #pragma unroll
    for (int qq = 0; qq < 8; ++qq) { ax[qq] = 0.f; ay[qq] = 0.f; }
    const int d2 = 2 * lane;
    const int kbase = wave * 8;      // this wave's k-slice within each tile

    for (int tt = 0; tt < 8; ++tt) {
        __syncthreads();             // also guards P/psumArr on first iter
        {   // stage V tile [k][128] unpadded (contiguous b128 writes)
            const float4* src = (const float4*)(Vb + (size_t)tt * 64 * DD);
            #pragma unroll
            for (int j = 0; j < 4; ++j) {
                int g = threadIdx.x + j * 512;
                ((float4*)KV)[g] = src[g];
            }
        }
        __syncthreads();

        #pragma unroll
        for (int kk = 0; kk < 8; kk += 4) {
            float4 pq[8];
            #pragma unroll
            for (int qq = 0; qq < 8; ++qq)
                pq[qq] = *(const float4*)&P[qq * 512 + tt * 64 + kbase + kk];
            #pragma unroll
            for (int j = 0; j < 4; ++j) {
                float2 v = *(const float2*)&KV[(kbase + kk + j) * 128 + d2];
                #pragma unroll
                for (int qq = 0; qq < 8; ++qq) {
                    float pj = ((const float*)&pq[qq])[j];
                    ax[qq] = fmaf(pj, v.x, ax[qq]);
                    ay[qq] = fmaf(pj, v.y, ay[qq]);
                }
            }
        }
    }

    // cross-wave log2 reduction through P's 16 KB
    float* R = P;
    __syncthreads();
    if (wave >= 4) {
        #pragma unroll
        for (int qq = 0; qq < 8; ++qq)
            *(float2*)&R[((wave - 4) * 8 + qq) * 128 + d2] = make_float2(ax[qq], ay[qq]);
    }
    __syncthreads();
    if (wave < 4) {
        #pragma unroll
        for (int qq = 0; qq < 8; ++qq) {
            float2 r = *(const float2*)&R[(wave * 8 + qq) * 128 + d2];
            ax[qq] += r.x; ay[qq] += r.y;
        }
    }
    __syncthreads();
    if (wave == 2 || wave == 3) {
        #pragma unroll
        for (int qq = 0; qq < 8; ++qq)
            *(float2*)&R[((wave - 2) * 8 + qq) * 128 + d2] = make_float2(ax[qq], ay[qq]);
    }
    __syncthreads();
    if (wave < 2) {
        #pragma unroll
        for (int qq = 0; qq < 8; ++qq) {
            float2 r = *(const float2*)&R[(wave * 8 + qq) * 128 + d2];
            ax[qq] += r.x; ay[qq] += r.y;
        }
    }
    __syncthreads();
    if (wave == 1) {
        #pragma unroll
        for (int qq = 0; qq < 8; ++qq)
            *(float2*)&R[qq * 128 + d2] = make_float2(ax[qq], ay[qq]);
    }
    __syncthreads();
    if (wave == 0) {
        #pragma unroll
        for (int qq = 0; qq < 8; ++qq) {
            float2 r = *(const float2*)&R[qq * 128 + d2];
            float inv = fast_rcp(psumArr[qq]);
            *(float2*)&out[(size_t)(q0 + qq) * DD + d2] =
                make_float2((ax[qq] + r.x) * inv, (ay[qq] + r.y) * inv);
        }
    }
}

// ---------------------------------------------------------------------------
extern "C" void kernel_launch(void* const* d_in, const int* in_sizes, int n_in,
                              void* d_out, int out_size, void* d_ws, size_t ws_size,
                              hipStream_t stream) {
    const float* query = (const float*)d_in[0];
    const float* key_  = (const float*)d_in[1];
    const float* value = (const float*)d_in[2];
    const float* Wq    = (const float*)d_in[3];
    const float* bq    = (const float*)d_in[4];
    const float* Wk    = (const float*)d_in[5];
    const float* bk    = (const float*)d_in[6];
    const float* Wv    = (const float*)d_in[7];
    const float* bv    = (const float*)d_in[8];
    const float* wd    = (const float*)d_in[9];
    const float* wsg   = (const float*)d_in[11];
    const float* wt    = (const float*)d_in[13];
    float* ws = (float*)d_ws;   // 3*MATN + 192 floats ~ 6.3 MB

    proj_kernel<<<384, 256, 0, stream>>>(query, key_, value,
                                         Wq, bq, Wk, bk, Wv, bv,
                                         wd, wsg, wt, ws);
    attn_kernel<<<512, 512, 0, stream>>>(ws, (float*)d_out);
}